// Round 14
// baseline (189.658 us; speedup 1.0000x reference)
//
#include <hip/hip_runtime.h>

// NW=32 wavelets, N=M=1024.
#define NPOINTS 1048576ULL
#define NWV 32
#define ZSTR 40   // h16 stride of [k1][n2] Z planes / F tables (16B-aligned rows)
#define PSTR 33   // u32 stride of stage plane [n2][n1] (odd -> <=2-way banks)

typedef _Float16 h8 __attribute__((ext_vector_type(8)));
typedef _Float16 h2 __attribute__((ext_vector_type(2)));
typedef short    s8v __attribute__((ext_vector_type(8)));
typedef float    f32x4 __attribute__((ext_vector_type(4)));

// Scaling plan (rounds 3-13): no 1/(N*M) in the FFTs; conv' = 2^20*conv.
// mod' = sqrt(|conv'|^2 + 1e-8*2^40); final scale 2^-60 in k_reduce.

__device__ __forceinline__ f32x4 MF(h8 a, h8 b, f32x4 c) {
    return __builtin_amdgcn_mfma_f32_16x16x32_f16(a, b, c, 0, 0, 0);
}
__device__ __forceinline__ h8 hneg(h8 x) {
    s8v s = *(s8v*)&x;
    s = s ^ (short)0x8000;
    return *(h8*)&s;
}
// sin/cos of (2*pi*rev): hardware trans ops take REVOLUTIONS (cdna4_isa §3).
__device__ __forceinline__ float fsin_rev(float rev) {
    float r; asm("v_sin_f32 %0, %1" : "=v"(r) : "v"(rev)); return r;
}
__device__ __forceinline__ float fcos_rev(float rev) {
    float r; asm("v_cos_f32 %0, %1" : "=v"(r) : "v"(rev)); return r;
}

// ---------------------------------------------------------------------------
// Tiny global trig tables (13 KB total, L1-resident on every CU; built once
// per launch). Values computed with the SAME v_sin/v_cos formulas the FFT
// kernels used inline in r10-r12 -> bit-identical results.
//   TWG[a*32+b] = W1024^(a*b)   (float2)
//   FGR/FGI[a*ZSTR+b] = W32^(a*b) re/im (f16 planes, b128-loadable rows)
// ---------------------------------------------------------------------------
__global__ void k_init_tables(float2* __restrict__ twg,
                              _Float16* __restrict__ fgr,
                              _Float16* __restrict__ fgi) {
    int i = blockIdx.x * 256 + threadIdx.x;   // 0..1023
    int a = i >> 5, b = i & 31;
    float rev1 = (float)(a * b) * (1.0f / 1024.0f);
    twg[a * 32 + b] = make_float2(fcos_rev(rev1), fsin_rev(rev1));
    float rev2 = (float)((a * b) & 31) * (1.0f / 32.0f);
    fgr[a * ZSTR + b] = (_Float16)fcos_rev(rev2);
    fgi[a * ZSTR + b] = (_Float16)fsin_rev(rev2);
}

// Unpack staged u32 (h2{re,im}) plane into MFMA A-fragments.
__device__ __forceinline__ void load_frags(const unsigned int* __restrict__ pl,
    int g, int c16, h8& ar0, h8& ai0, h8& ar1, h8& ai1)
{
    #pragma unroll
    for (int j = 0; j < 8; ++j) {
        unsigned int v0 = pl[PSTR * c16 + 8 * g + j];
        unsigned int v1 = pl[PSTR * (16 + c16) + 8 * g + j];
        h2 p0 = *(h2*)&v0, p1 = *(h2*)&v1;
        ar0[j] = p0.x; ai0[j] = p0.y;
        ar1[j] = p1.x; ai1[j] = p1.y;
    }
}

struct EOut { f32x4 r00, r01, r10, r11, i00, i01, i10, i11; };

// 1024-pt inverse FFT per wave, four-step 32x32 (validated rounds 7-13):
// TW twiddles read from the L1-hot global table (b64 gathers).
__device__ __forceinline__ EOut fft_core(
    h8 ar0, h8 ai0, h8 ar1, h8 ai1,
    h8 fr0, h8 fr1, h8 fi0, h8 fi1, h8 mfi0, h8 mfi1,
    const float2* __restrict__ twg,
    _Float16* __restrict__ Zr, _Float16* __restrict__ Zi,
    int g, int c16)
{
    const f32x4 z = {0.f, 0.f, 0.f, 0.f};
    f32x4 dr00=z, dr01=z, dr10=z, dr11=z, di00=z, di01=z, di10=z, di11=z;
    dr00 = MF(ar0, fr0, dr00); dr00 = MF(ai0, mfi0, dr00);
    di00 = MF(ar0, fi0, di00); di00 = MF(ai0, fr0,  di00);
    dr01 = MF(ar0, fr1, dr01); dr01 = MF(ai0, mfi1, dr01);
    di01 = MF(ar0, fi1, di01); di01 = MF(ai0, fr1,  di01);
    dr10 = MF(ar1, fr0, dr10); dr10 = MF(ai1, mfi0, dr10);
    di10 = MF(ar1, fi0, di10); di10 = MF(ai1, fr0,  di10);
    dr11 = MF(ar1, fr1, dr11); dr11 = MF(ai1, mfi1, dr11);
    di11 = MF(ar1, fi1, di11); di11 = MF(ai1, fr1,  di11);

#define TWZ(DR, DI, QI, QJ)                                                    \
    {                                                                          \
        const int k1 = 16 * (QJ) + c16;                                        \
        _Pragma("unroll")                                                      \
        for (int rp = 0; rp < 2; ++rp) {                                       \
            const int n2 = 16 * (QI) + 4 * g + 2 * rp;                         \
            float2 tA = twg[n2 * 32 + k1];                                     \
            float2 tB = twg[(n2 + 1) * 32 + k1];                               \
            float yr0 = DR[2*rp],   yi0 = DI[2*rp];                            \
            float yr1 = DR[2*rp+1], yi1 = DI[2*rp+1];                          \
            h2 zr2 = { (_Float16)(yr0*tA.x - yi0*tA.y),                        \
                       (_Float16)(yr1*tB.x - yi1*tB.y) };                      \
            h2 zi2 = { (_Float16)(yi0*tA.x + yr0*tA.y),                        \
                       (_Float16)(yi1*tB.x + yr1*tB.y) };                      \
            *(h2*)&Zr[k1 * ZSTR + n2] = zr2;                                   \
            *(h2*)&Zi[k1 * ZSTR + n2] = zi2;                                   \
        }                                                                      \
    }
    TWZ(dr00, di00, 0, 0) TWZ(dr01, di01, 0, 1)
    TWZ(dr10, di10, 1, 0) TWZ(dr11, di11, 1, 1)
#undef TWZ

    h8 a3r0 = *(h8*)&Zr[c16 * ZSTR + 8 * g];
    h8 a3i0 = *(h8*)&Zi[c16 * ZSTR + 8 * g];
    h8 a3r1 = *(h8*)&Zr[(16 + c16) * ZSTR + 8 * g];
    h8 a3i1 = *(h8*)&Zi[(16 + c16) * ZSTR + 8 * g];

    EOut e;
    e.r00 = MF(a3r0, fr0, z); e.r00 = MF(a3i0, mfi0, e.r00);
    e.i00 = MF(a3r0, fi0, z); e.i00 = MF(a3i0, fr0,  e.i00);
    e.r01 = MF(a3r0, fr1, z); e.r01 = MF(a3i0, mfi1, e.r01);
    e.i01 = MF(a3r0, fi1, z); e.i01 = MF(a3i0, fr1,  e.i01);
    e.r10 = MF(a3r1, fr0, z); e.r10 = MF(a3i1, mfi0, e.r10);
    e.i10 = MF(a3r1, fi0, z); e.i10 = MF(a3i1, fr0,  e.i10);
    e.r11 = MF(a3r1, fr1, z); e.r11 = MF(a3i1, mfi1, e.r11);
    e.i11 = MF(a3r1, fi1, z); e.i11 = MF(a3i1, fr1,  e.i11);
    return e;
}

// Load the F32 fragment set from the global tables (4 aligned b128 L1 hits).
__device__ __forceinline__ void load_f(const _Float16* __restrict__ fgr,
    const _Float16* __restrict__ fgi, int g, int c16,
    h8& fr0, h8& fi0, h8& fr1, h8& fi1, h8& mfi0, h8& mfi1)
{
    fr0 = *(const h8*)&fgr[c16 * ZSTR + 8 * g];
    fr1 = *(const h8*)&fgr[(16 + c16) * ZSTR + 8 * g];
    fi0 = *(const h8*)&fgi[c16 * ZSTR + 8 * g];
    fi1 = *(const h8*)&fgi[(16 + c16) * ZSTR + 8 * g];
    mfi0 = hneg(fi0); mfi1 = hneg(fi1);
}

// ---------------------------------------------------------------------------
// Pass A (r12 structure): 4 waves/block = 4 rows of one wavelet. All 16
// dwordx4 loads issued first, cmul+pack to stage plane, MFMA FFT, block
// transpose, coalesced stores to T[nb][k][4n]. LDS 21 KB -> ~60% occupancy.
// ---------------------------------------------------------------------------
__global__ __launch_bounds__(256, 4) void k_rowfft(
    const float* __restrict__ xhat, const float* __restrict__ pre,
    const float* __restrict__ pim, const float2* __restrict__ twg,
    const _Float16* __restrict__ fgr, const _Float16* __restrict__ fgi,
    unsigned int* __restrict__ T, int wbase)
{
    __shared__ unsigned int WSP[4][1312];   // per-wave stage/Z union; Ttile union
    const int t = threadIdx.x, wv = t >> 6, l = t & 63, g = l >> 4, c16 = l & 15;
    const int nb = blockIdx.x, n = nb * 4 + wv;
    const int wl = blockIdx.y, w = wbase + wl;

    // Issue ALL global loads first (16 x 16B in flight).
    const float4* pr4 = (const float4*)(pre + (size_t)w * NPOINTS + (size_t)n * 1024);
    const float4* pi4 = (const float4*)(pim + (size_t)w * NPOINTS + (size_t)n * 1024);
    const float4* xh4 = (const float4*)(xhat + (size_t)n * 2048);
    float4 A0 = pr4[l],        A1 = pr4[64 + l],     A2 = pr4[128 + l],     A3 = pr4[192 + l];
    float4 B0 = pi4[l],        B1 = pi4[64 + l],     B2 = pi4[128 + l],     B3 = pi4[192 + l];
    float4 Xa0 = xh4[2*l],     Xb0 = xh4[2*l + 1];
    float4 Xa1 = xh4[128 + 2*l], Xb1 = xh4[128 + 2*l + 1];
    float4 Xa2 = xh4[256 + 2*l], Xb2 = xh4[256 + 2*l + 1];
    float4 Xa3 = xh4[384 + 2*l], Xb3 = xh4[384 + 2*l + 1];

    h8 fr0, fi0, fr1, fi1, mfi0, mfi1;
    load_f(fgr, fgi, g, c16, fr0, fi0, fr1, fi1, mfi0, mfi1);  // L1 hits

    // Stage: m = 256c + 4l + i  ->  n1 = 8c + (l>>3), n2 = 4*(l&7) + i.
    unsigned int* pl = &WSP[wv][0];
    const int n2b = 4 * (l & 7), n1b = l >> 3;
#define STAGE(C, A, B, XA, XB)                                                 \
    {                                                                          \
        float xr[4] = {XA.x, XA.z, XB.x, XB.z};                                \
        float xi[4] = {XA.y, XA.w, XB.y, XB.w};                                \
        float pa[4] = {A.x, A.y, A.z, A.w};                                    \
        float pb[4] = {B.x, B.y, B.z, B.w};                                    \
        const int n1 = 8 * (C) + n1b;                                          \
        _Pragma("unroll")                                                      \
        for (int i = 0; i < 4; ++i) {                                          \
            float re = xr[i] * pa[i] - xi[i] * pb[i];                          \
            float im = xi[i] * pa[i] + xr[i] * pb[i];                          \
            h2 p = {(_Float16)re, (_Float16)im};                               \
            pl[PSTR * (n2b + i) + n1] = *(unsigned int*)&p;                    \
        }                                                                      \
    }
    STAGE(0, A0, B0, Xa0, Xb0) STAGE(1, A1, B1, Xa1, Xb1)
    STAGE(2, A2, B2, Xa2, Xb2) STAGE(3, A3, B3, Xa3, Xb3)
#undef STAGE

    h8 ar0, ai0, ar1, ai1;
    load_frags(pl, g, c16, ar0, ai0, ar1, ai1);   // intra-wave: no barrier

    EOut e = fft_core(ar0, ai0, ar1, ai1, fr0, fr1, fi0, fi1, mfi0, mfi1,
                      twg, (_Float16*)&WSP[wv][0], (_Float16*)&WSP[wv][0] + 1280,
                      g, c16);

    __syncthreads();                 // all waves done with private planes
    unsigned int* Ttile = &WSP[0][0];       // [k2]*132 + [k1]*4 + wv
#define EMIT(ER, EI, QI, QJ)                                                   \
    _Pragma("unroll")                                                          \
    for (int r = 0; r < 4; ++r) {                                              \
        int k1 = 16 * (QI) + 4 * g + r, k2 = 16 * (QJ) + c16;                  \
        h2 p = { (_Float16)ER[r], (_Float16)EI[r] };                           \
        Ttile[k2 * 132 + k1 * 4 + wv] = *(unsigned int*)&p;                    \
    }
    EMIT(e.r00, e.i00, 0, 0) EMIT(e.r01, e.i01, 0, 1)
    EMIT(e.r10, e.i10, 1, 0) EMIT(e.r11, e.i11, 1, 1)
#undef EMIT
    __syncthreads();

    // T[nb][k][j]: u32 idx = nb*4096 + k*4 + j. Consecutive t -> +16B.
    unsigned int* Tw = T + (size_t)wl * NPOINTS;
    #pragma unroll
    for (int jj = 0; jj < 4; ++jj) {
        int k = t + 256 * jj;
        uint4 v = *(uint4*)&Ttile[(k >> 5) * 132 + (k & 31) * 4];
        *(uint4*)&Tw[(size_t)nb * 4096 + (size_t)k * 4] = v;
    }
}

// ---------------------------------------------------------------------------
// Pass B (r12 structure): 4 waves/block = 4 consecutive columns. All 4 line
// loads first, scatter to wave planes, one barrier, MFMA FFT, modulus
// straight from registers (coalesced uint2 stores).
// ---------------------------------------------------------------------------
__global__ __launch_bounds__(256, 4) void k_colfft(
    const unsigned int* __restrict__ T, const float2* __restrict__ twg,
    const _Float16* __restrict__ fgr, const _Float16* __restrict__ fgi,
    _Float16* __restrict__ modb, int wbase)
{
    __shared__ unsigned int WSP[4][1312];
    const int t = threadIdx.x, wv = t >> 6, l = t & 63, g = l >> 4, c16 = l & 15;
    const int k0 = blockIdx.x * 4, k = k0 + wv;
    const int wl = blockIdx.y, w = wbase + wl;

    const unsigned int* Tc = T + (size_t)wl * NPOINTS;
    uint4 v0 = *(const uint4*)&Tc[(size_t)t * 4096 + (size_t)(k0 + 0) * 4];
    uint4 v1 = *(const uint4*)&Tc[(size_t)t * 4096 + (size_t)(k0 + 1) * 4];
    uint4 v2 = *(const uint4*)&Tc[(size_t)t * 4096 + (size_t)(k0 + 2) * 4];
    uint4 v3 = *(const uint4*)&Tc[(size_t)t * 4096 + (size_t)(k0 + 3) * 4];

    h8 fr0, fi0, fr1, fi1, mfi0, mfi1;
    load_f(fgr, fgi, g, c16, fr0, fi0, fr1, fi1, mfi0, mfi1);

    const int en2 = 4 * (t & 7), en1 = t >> 3;
#define SCAT(C, V)                                                             \
    {                                                                          \
        unsigned int* plc = &WSP[C][0];                                        \
        plc[PSTR * (en2 + 0) + en1] = V.x;                                     \
        plc[PSTR * (en2 + 1) + en1] = V.y;                                     \
        plc[PSTR * (en2 + 2) + en1] = V.z;                                     \
        plc[PSTR * (en2 + 3) + en1] = V.w;                                     \
    }
    SCAT(0, v0) SCAT(1, v1) SCAT(2, v2) SCAT(3, v3)
#undef SCAT
    __syncthreads();

    h8 ar0, ai0, ar1, ai1;
    load_frags(&WSP[wv][0], g, c16, ar0, ai0, ar1, ai1);

    EOut e = fft_core(ar0, ai0, ar1, ai1, fr0, fr1, fi0, fi1, mfi0, mfi1,
                      twg, (_Float16*)&WSP[wv][0], (_Float16*)&WSP[wv][0] + 1280,
                      g, c16);

    // mod straight from registers: u32 idx = 256*QJ + 16*c16 + 8*QI + 2*g + rp.
    unsigned int* mo = (unsigned int*)(modb + (size_t)w * NPOINTS + (size_t)k * 1024);
    const float epsp = 1.09951162778e4f;   // 1e-8 * 2^40
#define EMITM(ER, EI, QI, QJ)                                                  \
    {                                                                          \
        float m0 = sqrtf(ER[0]*ER[0] + EI[0]*EI[0] + epsp);                    \
        float m1 = sqrtf(ER[1]*ER[1] + EI[1]*EI[1] + epsp);                    \
        float m2 = sqrtf(ER[2]*ER[2] + EI[2]*EI[2] + epsp);                    \
        float m3 = sqrtf(ER[3]*ER[3] + EI[3]*EI[3] + epsp);                    \
        h2 ha = {(_Float16)m0, (_Float16)m1};                                  \
        h2 hb = {(_Float16)m2, (_Float16)m3};                                  \
        uint2 uv = { *(unsigned int*)&ha, *(unsigned int*)&hb };               \
        *(uint2*)&mo[256 * (QJ) + 16 * c16 + 8 * (QI) + 2 * g] = uv;           \
    }
    EMITM(e.r00, e.i00, 0, 0) EMITM(e.r01, e.i01, 0, 1)
    EMITM(e.r10, e.i10, 1, 0) EMITM(e.r11, e.i11, 1, 1)
#undef EMITM
}

// ---------------------------------------------------------------------------
// Pass C: Gram partials via MFMA (validated). 2048 partial rows.
// ---------------------------------------------------------------------------
__global__ __launch_bounds__(256) void k_gram(
    const _Float16* __restrict__ modb, float* __restrict__ part)
{
    __shared__ _Float16 tile[32][520];
    const int t = threadIdx.x;
    const int l = t & 63, wv = t >> 6;
    f32x4 c00 = {0.f,0.f,0.f,0.f}, c01 = {0.f,0.f,0.f,0.f}, c11 = {0.f,0.f,0.f,0.f};
    const size_t pbase = (size_t)blockIdx.x * 2048;

    for (int tt = 0; tt < 4; ++tt) {
        __syncthreads();
        size_t p0 = pbase + (size_t)tt * 512;
        #pragma unroll
        for (int i = 0; i < 8; ++i) {
            int w = i * 4 + wv;
            *(h8*)&tile[w][(size_t)(l * 8)] =
                *(const h8*)&modb[((size_t)w << 20) + p0 + (size_t)(l * 8)];
        }
        __syncthreads();
        #pragma unroll
        for (int s = 0; s < 4; ++s) {
            int k0 = (s * 4 + wv) * 32 + ((l >> 4) * 8);
            h8 a0 = *(const h8*)&tile[l & 15][k0];
            h8 a1 = *(const h8*)&tile[16 + (l & 15)][k0];
            c00 = __builtin_amdgcn_mfma_f32_16x16x32_f16(a0, a0, c00, 0, 0, 0);
            c01 = __builtin_amdgcn_mfma_f32_16x16x32_f16(a0, a1, c01, 0, 0, 0);
            c11 = __builtin_amdgcn_mfma_f32_16x16x32_f16(a1, a1, c11, 0, 0, 0);
        }
    }
    const int row = (blockIdx.x << 2) | wv;
    float* pr = part + ((size_t)row << 10);
    #pragma unroll
    for (int r = 0; r < 4; ++r) {
        int i = (l >> 4) * 4 + r;
        int j = l & 15;
        pr[i * 32 + j]             = c00[r];
        pr[i * 32 + 16 + j]        = c01[r];
        pr[(16 + i) * 32 + 16 + j] = c11[r];
    }
}

// ---------------------------------------------------------------------------
// Pass D: parallel reduce of part[2048][1024]; triangle map; scale 2^-60.
// ---------------------------------------------------------------------------
__global__ __launch_bounds__(256) void k_reduce(
    const float* __restrict__ part, float* __restrict__ out)
{
    __shared__ float red[16][17];
    const int t = threadIdx.x;
    const int sl    = t & 15;
    const int chunk = t >> 4;
    const int slot  = blockIdx.x * 16 + sl;
    float v = 0.0f;
    const int r0 = chunk * 128;
    for (int i = 0; i < 128; ++i)
        v += part[((size_t)(r0 + i) << 10) + slot];
    red[chunk][sl] = v;
    __syncthreads();
    if (t < 16) {
        float s = 0.0f;
        #pragma unroll
        for (int cch = 0; cch < 16; ++cch) s += red[cch][t];
        int sq = blockIdx.x * 16 + t;
        int i = sq >> 5, j = sq & 31;
        if (j >= i) {
            int q = 32 * i - (i * (i - 1)) / 2 + (j - i);
            if (q < 527) out[q] = s * 8.6736173798840355e-19f;   // 2^-60
        }
    }
}

// ---------------------------------------------------------------------------
extern "C" void kernel_launch(void* const* d_in, const int* in_sizes, int n_in,
                              void* d_out, int out_size, void* d_ws, size_t ws_size,
                              hipStream_t stream) {
    (void)in_sizes; (void)n_in; (void)out_size;
    const float*  xhat = (const float*)d_in[0];
    const float*  pre  = (const float*)d_in[1];
    const float*  pim  = (const float*)d_in[2];
    float* out = (float*)d_out;

    char* ws = (char*)d_ws;
    _Float16*     modb = (_Float16*)ws;                              // 64 MB
    float*        part = (float*)(ws + NWV * NPOINTS * 2ULL);        // 8 MB
    size_t        tabo = NWV * NPOINTS * 2ULL + 2048ULL * 1024ULL * 4ULL;
    float2*       twg  = (float2*)(ws + tabo);                       // 8 KB
    _Float16*     fgr  = (_Float16*)(ws + tabo + 16384);             // 2.5 KB
    _Float16*     fgi  = (_Float16*)(ws + tabo + 32768);             // 2.5 KB
    size_t        Toff = tabo + 65536;
    unsigned int* T    = (unsigned int*)(ws + Toff);                 // WB*4 MB

    // WB=32 preferred: 5 dispatches total, no inter-batch serialization.
    int WB = 1;
    const int cands[6] = {32, 16, 8, 4, 2, 1};
    for (int c = 0; c < 6; ++c)
        if (Toff + (size_t)cands[c] * NPOINTS * 4ULL <= ws_size) { WB = cands[c]; break; }

    hipLaunchKernelGGL(k_init_tables, dim3(4), dim3(256), 0, stream, twg, fgr, fgi);
    for (int wb = 0; wb < NWV; wb += WB) {
        hipLaunchKernelGGL(k_rowfft, dim3(256, WB), dim3(256), 0, stream,
                           xhat, pre, pim, (const float2*)twg,
                           (const _Float16*)fgr, (const _Float16*)fgi, T, wb);
        hipLaunchKernelGGL(k_colfft, dim3(256, WB), dim3(256), 0, stream,
                           (const unsigned int*)T, (const float2*)twg,
                           (const _Float16*)fgr, (const _Float16*)fgi, modb, wb);
    }
    hipLaunchKernelGGL(k_gram, dim3(512), dim3(256), 0, stream,
                       (const _Float16*)modb, part);
    hipLaunchKernelGGL(k_reduce, dim3(64), dim3(256), 0, stream,
                       (const float*)part, out);
}

// Round 15
// 156.887 us; speedup vs baseline: 1.2089x; 1.2089x over previous
//
#include <hip/hip_runtime.h>

// NW=32 wavelets, N=M=1024.
#define NPOINTS 1048576ULL
#define NWV 32
#define ZSTR 40   // h16 stride of [k1][n2] Z planes (16B-aligned rows)
#define PSTR 33   // u32 stride of stage plane [n2][n1] (odd -> <=2-way banks)

typedef _Float16 h8 __attribute__((ext_vector_type(8)));
typedef _Float16 h2 __attribute__((ext_vector_type(2)));
typedef short    s8v __attribute__((ext_vector_type(8)));
typedef float    f32x4 __attribute__((ext_vector_type(4)));

// Scaling plan (rounds 3-14): no 1/(N*M) in the FFTs; conv' = 2^20*conv.
// mod' = sqrt(|conv'|^2 + 1e-8*2^40); final scale 2^-60 in k_reduce.

__device__ __forceinline__ f32x4 MF(h8 a, h8 b, f32x4 c) {
    return __builtin_amdgcn_mfma_f32_16x16x32_f16(a, b, c, 0, 0, 0);
}
__device__ __forceinline__ h8 hneg(h8 x) {
    s8v s = *(s8v*)&x;
    s = s ^ (short)0x8000;
    return *(h8*)&s;
}
// sin/cos of (2*pi*rev): hardware trans ops take REVOLUTIONS (cdna4_isa §3).
__device__ __forceinline__ float fsin_rev(float rev) {
    float r; asm("v_sin_f32 %0, %1" : "=v"(r) : "v"(rev)); return r;
}
__device__ __forceinline__ float fcos_rev(float rev) {
    float r; asm("v_cos_f32 %0, %1" : "=v"(r) : "v"(rev)); return r;
}
__device__ __forceinline__ float2 cmulf(float2 a, float2 b) {
    return make_float2(a.x * b.x - a.y * b.y, a.x * b.y + a.y * b.x);
}

// Per-lane F32 fragments via geometric recurrence: W32^(c16*b) over b=8g..8g+7
// is base*ratio^j (4 trans + 7 cmuls, was 64 trans). Row c16+16 = (-1)^j row
// c16 (W32^16 = -1) -> pure sign flips. Error <= ~4e-7 rel, << f16 rounding.
__device__ __forceinline__ void build_ffrags(int g, int c16,
    h8& fr0, h8& fi0, h8& fr1, h8& fi1)
{
    float rb = (float)((8 * g * c16) & 31) * (1.0f / 32.0f);
    float rr = (float)c16 * (1.0f / 32.0f);
    float2 wv_ = make_float2(fcos_rev(rb), fsin_rev(rb));
    float2 rat = make_float2(fcos_rev(rr), fsin_rev(rr));
    #pragma unroll
    for (int j = 0; j < 8; ++j) {
        fr0[j] = (_Float16)wv_.x; fi0[j] = (_Float16)wv_.y;
        if (j & 1) { fr1[j] = (_Float16)(-wv_.x); fi1[j] = (_Float16)(-wv_.y); }
        else       { fr1[j] = (_Float16)( wv_.x); fi1[j] = (_Float16)( wv_.y); }
        wv_ = cmulf(wv_, rat);
    }
}

// Unpack staged u32 (h2{re,im}) plane into MFMA A-fragments.
__device__ __forceinline__ void load_frags(const unsigned int* __restrict__ pl,
    int g, int c16, h8& ar0, h8& ai0, h8& ar1, h8& ai1)
{
    #pragma unroll
    for (int j = 0; j < 8; ++j) {
        unsigned int v0 = pl[PSTR * c16 + 8 * g + j];
        unsigned int v1 = pl[PSTR * (16 + c16) + 8 * g + j];
        h2 p0 = *(h2*)&v0, p1 = *(h2*)&v1;
        ar0[j] = p0.x; ai0[j] = p0.y;
        ar1[j] = p1.x; ai1[j] = p1.y;
    }
}

struct EOut { f32x4 r00, r01, r10, r11, i00, i01, i10, i11; };

// 1024-pt inverse FFT per wave, four-step 32x32 (validated rounds 7-14).
// TWZ twiddles: geometric chain per quadrant — exponents n2base*k1 + {0..3}*k1;
// one base (2 trans) per (QI,QJ) + one step W1024^k1 per QJ, rest by cmul.
// 12 trans + 48 VALU replaces r12's 64 trans. All temporaries macro-local.
__device__ __forceinline__ EOut fft_core(
    h8 ar0, h8 ai0, h8 ar1, h8 ai1,
    h8 fr0, h8 fr1, h8 fi0, h8 fi1, h8 mfi0, h8 mfi1,
    _Float16* __restrict__ Zr, _Float16* __restrict__ Zi,
    int g, int c16)
{
    const f32x4 z = {0.f, 0.f, 0.f, 0.f};
    f32x4 dr00=z, dr01=z, dr10=z, dr11=z, di00=z, di01=z, di10=z, di11=z;
    dr00 = MF(ar0, fr0, dr00); dr00 = MF(ai0, mfi0, dr00);
    di00 = MF(ar0, fi0, di00); di00 = MF(ai0, fr0,  di00);
    dr01 = MF(ar0, fr1, dr01); dr01 = MF(ai0, mfi1, dr01);
    di01 = MF(ar0, fi1, di01); di01 = MF(ai0, fr1,  di01);
    dr10 = MF(ar1, fr0, dr10); dr10 = MF(ai1, mfi0, dr10);
    di10 = MF(ar1, fi0, di10); di10 = MF(ai1, fr0,  di10);
    dr11 = MF(ar1, fr1, dr11); dr11 = MF(ai1, mfi1, dr11);
    di11 = MF(ar1, fi1, di11); di11 = MF(ai1, fr1,  di11);

    // Per-QJ steps W1024^k1 (4 trans total).
    float2 st0 = make_float2(fcos_rev((float)c16 * (1.0f / 1024.0f)),
                             fsin_rev((float)c16 * (1.0f / 1024.0f)));
    float2 st1 = make_float2(fcos_rev((float)(16 + c16) * (1.0f / 1024.0f)),
                             fsin_rev((float)(16 + c16) * (1.0f / 1024.0f)));

#define TWZ(DR, DI, QI, QJ)                                                    \
    {                                                                          \
        const int k1 = 16 * (QJ) + c16;                                        \
        const int n2base = 16 * (QI) + 4 * g;                                  \
        const float2 st = (QJ) ? st1 : st0;                                    \
        float rb = (float)(n2base * k1) * (1.0f / 1024.0f);  /* < 1: 868max */ \
        float2 t0 = make_float2(fcos_rev(rb), fsin_rev(rb));                   \
        float2 t1 = cmulf(t0, st);                                             \
        float2 t2 = cmulf(t1, st);                                             \
        float2 t3 = cmulf(t2, st);                                             \
        {                                                                      \
            float yr0 = DR[0], yi0 = DI[0], yr1 = DR[1], yi1 = DI[1];          \
            h2 zr2 = { (_Float16)(yr0*t0.x - yi0*t0.y),                        \
                       (_Float16)(yr1*t1.x - yi1*t1.y) };                      \
            h2 zi2 = { (_Float16)(yi0*t0.x + yr0*t0.y),                        \
                       (_Float16)(yi1*t1.x + yr1*t1.y) };                      \
            *(h2*)&Zr[k1 * ZSTR + n2base] = zr2;                               \
            *(h2*)&Zi[k1 * ZSTR + n2base] = zi2;                               \
        }                                                                      \
        {                                                                      \
            float yr0 = DR[2], yi0 = DI[2], yr1 = DR[3], yi1 = DI[3];          \
            h2 zr2 = { (_Float16)(yr0*t2.x - yi0*t2.y),                        \
                       (_Float16)(yr1*t3.x - yi1*t3.y) };                      \
            h2 zi2 = { (_Float16)(yi0*t2.x + yr0*t2.y),                        \
                       (_Float16)(yi1*t3.x + yr1*t3.y) };                      \
            *(h2*)&Zr[k1 * ZSTR + n2base + 2] = zr2;                           \
            *(h2*)&Zi[k1 * ZSTR + n2base + 2] = zi2;                           \
        }                                                                      \
    }
    TWZ(dr00, di00, 0, 0) TWZ(dr01, di01, 0, 1)
    TWZ(dr10, di10, 1, 0) TWZ(dr11, di11, 1, 1)
#undef TWZ

    h8 a3r0 = *(h8*)&Zr[c16 * ZSTR + 8 * g];
    h8 a3i0 = *(h8*)&Zi[c16 * ZSTR + 8 * g];
    h8 a3r1 = *(h8*)&Zr[(16 + c16) * ZSTR + 8 * g];
    h8 a3i1 = *(h8*)&Zi[(16 + c16) * ZSTR + 8 * g];

    EOut e;
    e.r00 = MF(a3r0, fr0, z); e.r00 = MF(a3i0, mfi0, e.r00);
    e.i00 = MF(a3r0, fi0, z); e.i00 = MF(a3i0, fr0,  e.i00);
    e.r01 = MF(a3r0, fr1, z); e.r01 = MF(a3i0, mfi1, e.r01);
    e.i01 = MF(a3r0, fi1, z); e.i01 = MF(a3i0, fr1,  e.i01);
    e.r10 = MF(a3r1, fr0, z); e.r10 = MF(a3i1, mfi0, e.r10);
    e.i10 = MF(a3r1, fi0, z); e.i10 = MF(a3i1, fr0,  e.i10);
    e.r11 = MF(a3r1, fr1, z); e.r11 = MF(a3i1, mfi1, e.r11);
    e.i11 = MF(a3r1, fi1, z); e.i11 = MF(a3i1, fr1,  e.i11);
    return e;
}

// ---------------------------------------------------------------------------
// Pass A (r12 structure): 4 waves/block = 4 rows of one wavelet. All 16
// dwordx4 loads issued first, cmul+pack to stage plane, MFMA FFT, block
// transpose, coalesced stores to T[nb][k][4n]. LDS 21 KB -> ~60% occupancy.
// ---------------------------------------------------------------------------
__global__ __launch_bounds__(256, 4) void k_rowfft(
    const float* __restrict__ xhat, const float* __restrict__ pre,
    const float* __restrict__ pim, unsigned int* __restrict__ T, int wbase)
{
    __shared__ unsigned int WSP[4][1312];   // per-wave stage/Z union; Ttile union
    const int t = threadIdx.x, wv = t >> 6, l = t & 63, g = l >> 4, c16 = l & 15;
    const int nb = blockIdx.x, n = nb * 4 + wv;
    const int wl = blockIdx.y, w = wbase + wl;

    // Issue ALL global loads first (16 x 16B in flight).
    const float4* pr4 = (const float4*)(pre + (size_t)w * NPOINTS + (size_t)n * 1024);
    const float4* pi4 = (const float4*)(pim + (size_t)w * NPOINTS + (size_t)n * 1024);
    const float4* xh4 = (const float4*)(xhat + (size_t)n * 2048);
    float4 A0 = pr4[l],        A1 = pr4[64 + l],     A2 = pr4[128 + l],     A3 = pr4[192 + l];
    float4 B0 = pi4[l],        B1 = pi4[64 + l],     B2 = pi4[128 + l],     B3 = pi4[192 + l];
    float4 Xa0 = xh4[2*l],     Xb0 = xh4[2*l + 1];
    float4 Xa1 = xh4[128 + 2*l], Xb1 = xh4[128 + 2*l + 1];
    float4 Xa2 = xh4[256 + 2*l], Xb2 = xh4[256 + 2*l + 1];
    float4 Xa3 = xh4[384 + 2*l], Xb3 = xh4[384 + 2*l + 1];

    h8 fr0, fi0, fr1, fi1;
    build_ffrags(g, c16, fr0, fi0, fr1, fi1);   // 4 trans; overlaps load latency
    h8 mfi0 = hneg(fi0), mfi1 = hneg(fi1);

    // Stage: m = 256c + 4l + i  ->  n1 = 8c + (l>>3), n2 = 4*(l&7) + i.
    unsigned int* pl = &WSP[wv][0];
    const int n2b = 4 * (l & 7), n1b = l >> 3;
#define STAGE(C, A, B, XA, XB)                                                 \
    {                                                                          \
        float xr[4] = {XA.x, XA.z, XB.x, XB.z};                                \
        float xi[4] = {XA.y, XA.w, XB.y, XB.w};                                \
        float pa[4] = {A.x, A.y, A.z, A.w};                                    \
        float pb[4] = {B.x, B.y, B.z, B.w};                                    \
        const int n1 = 8 * (C) + n1b;                                          \
        _Pragma("unroll")                                                      \
        for (int i = 0; i < 4; ++i) {                                          \
            float re = xr[i] * pa[i] - xi[i] * pb[i];                          \
            float im = xi[i] * pa[i] + xr[i] * pb[i];                          \
            h2 p = {(_Float16)re, (_Float16)im};                               \
            pl[PSTR * (n2b + i) + n1] = *(unsigned int*)&p;                    \
        }                                                                      \
    }
    STAGE(0, A0, B0, Xa0, Xb0) STAGE(1, A1, B1, Xa1, Xb1)
    STAGE(2, A2, B2, Xa2, Xb2) STAGE(3, A3, B3, Xa3, Xb3)
#undef STAGE

    h8 ar0, ai0, ar1, ai1;
    load_frags(pl, g, c16, ar0, ai0, ar1, ai1);   // intra-wave: no barrier

    EOut e = fft_core(ar0, ai0, ar1, ai1, fr0, fr1, fi0, fi1, mfi0, mfi1,
                      (_Float16*)&WSP[wv][0], (_Float16*)&WSP[wv][0] + 1280,
                      g, c16);

    __syncthreads();                 // all waves done with private planes
    unsigned int* Ttile = &WSP[0][0];       // [k2]*132 + [k1]*4 + wv
#define EMIT(ER, EI, QI, QJ)                                                   \
    _Pragma("unroll")                                                          \
    for (int r = 0; r < 4; ++r) {                                              \
        int k1 = 16 * (QI) + 4 * g + r, k2 = 16 * (QJ) + c16;                  \
        h2 p = { (_Float16)ER[r], (_Float16)EI[r] };                           \
        Ttile[k2 * 132 + k1 * 4 + wv] = *(unsigned int*)&p;                    \
    }
    EMIT(e.r00, e.i00, 0, 0) EMIT(e.r01, e.i01, 0, 1)
    EMIT(e.r10, e.i10, 1, 0) EMIT(e.r11, e.i11, 1, 1)
#undef EMIT
    __syncthreads();

    // T[nb][k][j]: u32 idx = nb*4096 + k*4 + j. Consecutive t -> +16B.
    unsigned int* Tw = T + (size_t)wl * NPOINTS;
    #pragma unroll
    for (int jj = 0; jj < 4; ++jj) {
        int k = t + 256 * jj;
        uint4 v = *(uint4*)&Ttile[(k >> 5) * 132 + (k & 31) * 4];
        *(uint4*)&Tw[(size_t)nb * 4096 + (size_t)k * 4] = v;
    }
}

// ---------------------------------------------------------------------------
// Pass B (r12 structure): 4 waves/block = 4 consecutive columns. All 4 line
// loads first, scatter to wave planes, one barrier, MFMA FFT, modulus
// straight from registers (coalesced uint2 stores).
// ---------------------------------------------------------------------------
__global__ __launch_bounds__(256, 4) void k_colfft(
    const unsigned int* __restrict__ T, _Float16* __restrict__ modb, int wbase)
{
    __shared__ unsigned int WSP[4][1312];
    const int t = threadIdx.x, wv = t >> 6, l = t & 63, g = l >> 4, c16 = l & 15;
    const int k0 = blockIdx.x * 4, k = k0 + wv;
    const int wl = blockIdx.y, w = wbase + wl;

    const unsigned int* Tc = T + (size_t)wl * NPOINTS;
    uint4 v0 = *(const uint4*)&Tc[(size_t)t * 4096 + (size_t)(k0 + 0) * 4];
    uint4 v1 = *(const uint4*)&Tc[(size_t)t * 4096 + (size_t)(k0 + 1) * 4];
    uint4 v2 = *(const uint4*)&Tc[(size_t)t * 4096 + (size_t)(k0 + 2) * 4];
    uint4 v3 = *(const uint4*)&Tc[(size_t)t * 4096 + (size_t)(k0 + 3) * 4];

    h8 fr0, fi0, fr1, fi1;
    build_ffrags(g, c16, fr0, fi0, fr1, fi1);
    h8 mfi0 = hneg(fi0), mfi1 = hneg(fi1);

    const int en2 = 4 * (t & 7), en1 = t >> 3;
#define SCAT(C, V)                                                             \
    {                                                                          \
        unsigned int* plc = &WSP[C][0];                                        \
        plc[PSTR * (en2 + 0) + en1] = V.x;                                     \
        plc[PSTR * (en2 + 1) + en1] = V.y;                                     \
        plc[PSTR * (en2 + 2) + en1] = V.z;                                     \
        plc[PSTR * (en2 + 3) + en1] = V.w;                                     \
    }
    SCAT(0, v0) SCAT(1, v1) SCAT(2, v2) SCAT(3, v3)
#undef SCAT
    __syncthreads();

    h8 ar0, ai0, ar1, ai1;
    load_frags(&WSP[wv][0], g, c16, ar0, ai0, ar1, ai1);

    EOut e = fft_core(ar0, ai0, ar1, ai1, fr0, fr1, fi0, fi1, mfi0, mfi1,
                      (_Float16*)&WSP[wv][0], (_Float16*)&WSP[wv][0] + 1280,
                      g, c16);

    // mod straight from registers: u32 idx = 256*QJ + 16*c16 + 8*QI + 2*g + rp.
    unsigned int* mo = (unsigned int*)(modb + (size_t)w * NPOINTS + (size_t)k * 1024);
    const float epsp = 1.09951162778e4f;   // 1e-8 * 2^40
#define EMITM(ER, EI, QI, QJ)                                                  \
    {                                                                          \
        float m0 = sqrtf(ER[0]*ER[0] + EI[0]*EI[0] + epsp);                    \
        float m1 = sqrtf(ER[1]*ER[1] + EI[1]*EI[1] + epsp);                    \
        float m2 = sqrtf(ER[2]*ER[2] + EI[2]*EI[2] + epsp);                    \
        float m3 = sqrtf(ER[3]*ER[3] + EI[3]*EI[3] + epsp);                    \
        h2 ha = {(_Float16)m0, (_Float16)m1};                                  \
        h2 hb = {(_Float16)m2, (_Float16)m3};                                  \
        uint2 uv = { *(unsigned int*)&ha, *(unsigned int*)&hb };               \
        *(uint2*)&mo[256 * (QJ) + 16 * c16 + 8 * (QI) + 2 * g] = uv;           \
    }
    EMITM(e.r00, e.i00, 0, 0) EMITM(e.r01, e.i01, 0, 1)
    EMITM(e.r10, e.i10, 1, 0) EMITM(e.r11, e.i11, 1, 1)
#undef EMITM
}

// ---------------------------------------------------------------------------
// Pass C: Gram partials via MFMA (validated). 2048 partial rows.
// ---------------------------------------------------------------------------
__global__ __launch_bounds__(256) void k_gram(
    const _Float16* __restrict__ modb, float* __restrict__ part)
{
    __shared__ _Float16 tile[32][520];
    const int t = threadIdx.x;
    const int l = t & 63, wv = t >> 6;
    f32x4 c00 = {0.f,0.f,0.f,0.f}, c01 = {0.f,0.f,0.f,0.f}, c11 = {0.f,0.f,0.f,0.f};
    const size_t pbase = (size_t)blockIdx.x * 2048;

    for (int tt = 0; tt < 4; ++tt) {
        __syncthreads();
        size_t p0 = pbase + (size_t)tt * 512;
        #pragma unroll
        for (int i = 0; i < 8; ++i) {
            int w = i * 4 + wv;
            *(h8*)&tile[w][(size_t)(l * 8)] =
                *(const h8*)&modb[((size_t)w << 20) + p0 + (size_t)(l * 8)];
        }
        __syncthreads();
        #pragma unroll
        for (int s = 0; s < 4; ++s) {
            int k0 = (s * 4 + wv) * 32 + ((l >> 4) * 8);
            h8 a0 = *(const h8*)&tile[l & 15][k0];
            h8 a1 = *(const h8*)&tile[16 + (l & 15)][k0];
            c00 = __builtin_amdgcn_mfma_f32_16x16x32_f16(a0, a0, c00, 0, 0, 0);
            c01 = __builtin_amdgcn_mfma_f32_16x16x32_f16(a0, a1, c01, 0, 0, 0);
            c11 = __builtin_amdgcn_mfma_f32_16x16x32_f16(a1, a1, c11, 0, 0, 0);
        }
    }
    const int row = (blockIdx.x << 2) | wv;
    float* pr = part + ((size_t)row << 10);
    #pragma unroll
    for (int r = 0; r < 4; ++r) {
        int i = (l >> 4) * 4 + r;
        int j = l & 15;
        pr[i * 32 + j]             = c00[r];
        pr[i * 32 + 16 + j]        = c01[r];
        pr[(16 + i) * 32 + 16 + j] = c11[r];
    }
}

// ---------------------------------------------------------------------------
// Pass D: parallel reduce of part[2048][1024]; triangle map; scale 2^-60.
// ---------------------------------------------------------------------------
__global__ __launch_bounds__(256) void k_reduce(
    const float* __restrict__ part, float* __restrict__ out)
{
    __shared__ float red[16][17];
    const int t = threadIdx.x;
    const int sl    = t & 15;
    const int chunk = t >> 4;
    const int slot  = blockIdx.x * 16 + sl;
    float v = 0.0f;
    const int r0 = chunk * 128;
    for (int i = 0; i < 128; ++i)
        v += part[((size_t)(r0 + i) << 10) + slot];
    red[chunk][sl] = v;
    __syncthreads();
    if (t < 16) {
        float s = 0.0f;
        #pragma unroll
        for (int cch = 0; cch < 16; ++cch) s += red[cch][t];
        int sq = blockIdx.x * 16 + t;
        int i = sq >> 5, j = sq & 31;
        if (j >= i) {
            int q = 32 * i - (i * (i - 1)) / 2 + (j - i);
            if (q < 527) out[q] = s * 8.6736173798840355e-19f;   // 2^-60
        }
    }
}

// ---------------------------------------------------------------------------
extern "C" void kernel_launch(void* const* d_in, const int* in_sizes, int n_in,
                              void* d_out, int out_size, void* d_ws, size_t ws_size,
                              hipStream_t stream) {
    (void)in_sizes; (void)n_in; (void)out_size;
    const float*  xhat = (const float*)d_in[0];
    const float*  pre  = (const float*)d_in[1];
    const float*  pim  = (const float*)d_in[2];
    float* out = (float*)d_out;

    char* ws = (char*)d_ws;
    _Float16*     modb = (_Float16*)ws;                              // 64 MB
    float*        part = (float*)(ws + NWV * NPOINTS * 2ULL);        // 8 MB
    size_t        Toff = NWV * NPOINTS * 2ULL + 2048ULL * 1024ULL * 4ULL;
    unsigned int* T    = (unsigned int*)(ws + Toff);                 // WB*4 MB

    // WB=32 preferred: 4 dispatches total, no inter-batch serialization.
    int WB = 1;
    const int cands[6] = {32, 16, 8, 4, 2, 1};
    for (int c = 0; c < 6; ++c)
        if (Toff + (size_t)cands[c] * NPOINTS * 4ULL <= ws_size) { WB = cands[c]; break; }

    for (int wb = 0; wb < NWV; wb += WB) {
        hipLaunchKernelGGL(k_rowfft, dim3(256, WB), dim3(256), 0, stream,
                           xhat, pre, pim, T, wb);
        hipLaunchKernelGGL(k_colfft, dim3(256, WB), dim3(256), 0, stream,
                           (const unsigned int*)T, modb, wb);
    }
    hipLaunchKernelGGL(k_gram, dim3(512), dim3(256), 0, stream,
                       (const _Float16*)modb, part);
    hipLaunchKernelGGL(k_reduce, dim3(64), dim3(256), 0, stream,
                       (const float*)part, out);
}